// Round 4
// baseline (723.518 us; speedup 1.0000x reference)
//
#include <hip/hip_runtime.h>
#include <hip/hip_bf16.h>

#define NN 100000
#define EE 500000
#define BB 4096
#define HC 128
#define SCAN_ELEM 1024
#define NSB ((NN + SCAN_ELEM - 1) / SCAN_ELEM)   // 98 blocks

typedef __bf16 bf16_t;
typedef bf16_t bf16x8 __attribute__((ext_vector_type(8)));
typedef float f32x4 __attribute__((ext_vector_type(4)));
typedef float f32x2 __attribute__((ext_vector_type(2)));

__device__ __forceinline__ unsigned short f2bf(float f) {
    unsigned u = __builtin_bit_cast(unsigned, f);
    u += 0x7FFFu + ((u >> 16) & 1u);            // RNE
    return (unsigned short)(u >> 16);
}
__device__ __forceinline__ float bflo(unsigned u) {   // low bf16 -> f32
    return __builtin_bit_cast(float, u << 16);
}
__device__ __forceinline__ float bfhi(unsigned u) {   // high bf16 -> f32
    return __builtin_bit_cast(float, u & 0xFFFF0000u);
}
__device__ __forceinline__ f32x2 unpk2(unsigned u) {  // packed pair -> 2 f32
    return (f32x2){ bflo(u), bfhi(u) };
}

// ---- convert fp32 -> bf16, 4 elems/thread ----------------------------------
__global__ __launch_bounds__(256) void conv_x(const float* __restrict__ in,
                                              unsigned short* __restrict__ outb,
                                              int total4)
{
    const int g = blockIdx.x * 256 + threadIdx.x;
    if (g >= total4) return;
    const float4 f = *(const float4*)(in + (size_t)g * 4);
    ushort4 u;
    u.x = f2bf(f.x); u.y = f2bf(f.y); u.z = f2bf(f.z); u.w = f2bf(f.w);
    *(ushort4*)(outb + (size_t)g * 4) = u;
}

// ---- convert + transpose weights: W[k,n] fp32 -> Wt[p][n*K+k] bf16 ---------
__global__ __launch_bounds__(256) void prep_w(
    const float* __restrict__ Wq, const float* __restrict__ Wk,
    const float* __restrict__ Wv, const float* __restrict__ Ws,
    unsigned short* __restrict__ Wt, int K)
{
    const int g = blockIdx.x * 256 + threadIdx.x;
    const int per = K * 128;
    if (g >= 4 * per) return;
    const int p = g / per, r = g - p * per;
    const int k = r >> 7, n = r & 127;
    const float* W = p == 0 ? Wq : p == 1 ? Wk : p == 2 ? Wv : Ws;
    Wt[(size_t)p * per + (size_t)n * K + k] = f2bf(W[k * 128 + n]);
}

// ---- MFMA GEMM: block = 4 waves = 4 planes, 32-row tile, 128 cols ----------
// Q packed bf16 (stride 64 dwords); K,V interleaved in KVb rows of 128 dwords
// (K at +0, V at +64) so the edge kernel computes ONE gather address per edge.
// S (skip) stored fp32.
template<int NKT>
__global__ __launch_bounds__(256) void gemm_mfma(
    const unsigned short* __restrict__ A,
    const unsigned short* __restrict__ Wt,
    const float* __restrict__ bq, const float* __restrict__ bk,
    const float* __restrict__ bv, const float* __restrict__ bs,
    unsigned* __restrict__ Qb, unsigned* __restrict__ KVb,
    float* __restrict__ S)
{
    constexpr int K = NKT * 32;
    const int lane = threadIdx.x & 63;
    const int p = threadIdx.x >> 6;              // wave == plane
    const int m = lane & 15, kq = lane >> 4;
    const int rows0 = blockIdx.x * 32;

    const unsigned short* Wp = Wt + (size_t)p * 128 * K;
    const float* bias = p == 0 ? bq : p == 1 ? bk : p == 2 ? bv : bs;

    bf16x8 a[2][NKT];
#pragma unroll
    for (int mt = 0; mt < 2; mt++)
#pragma unroll
        for (int kt = 0; kt < NKT; kt++)
            a[mt][kt] = *(const bf16x8*)(A + (size_t)(rows0 + mt * 16 + m) * K + kt * 32 + kq * 8);

    f32x4 acc[2][8];
#pragma unroll
    for (int mt = 0; mt < 2; mt++)
#pragma unroll
        for (int nt = 0; nt < 8; nt++)
            acc[mt][nt] = (f32x4){0.f, 0.f, 0.f, 0.f};

#pragma unroll
    for (int nt = 0; nt < 8; nt++) {
#pragma unroll
        for (int kt = 0; kt < NKT; kt++) {
            const bf16x8 b = *(const bf16x8*)(Wp + (size_t)(nt * 16 + m) * K + kt * 32 + kq * 8);
            acc[0][nt] = __builtin_amdgcn_mfma_f32_16x16x32_bf16(a[0][kt], b, acc[0][nt], 0, 0, 0);
            acc[1][nt] = __builtin_amdgcn_mfma_f32_16x16x32_bf16(a[1][kt], b, acc[1][nt], 0, 0, 0);
        }
    }

    if (p == 3) {
#pragma unroll
        for (int nt = 0; nt < 8; nt++) {
            const float bi = bias[nt * 16 + m];
#pragma unroll
            for (int mt = 0; mt < 2; mt++) {
                float* o = S + (size_t)(rows0 + mt * 16 + kq * 4) * HC + nt * 16 + m;
#pragma unroll
                for (int r = 0; r < 4; r++) o[r * HC] = acc[mt][nt][r] + bi;
            }
        }
    } else {
        unsigned* out = p == 0 ? Qb : (p == 1 ? KVb : KVb + 64);
        const int stride = p == 0 ? 64 : 128;
#pragma unroll
        for (int nt = 0; nt < 8; nt++) {
            const float bi = bias[nt * 16 + m];
#pragma unroll
            for (int mt = 0; mt < 2; mt++) {
#pragma unroll
                for (int r = 0; r < 4; r++) {
                    const float v0 = acc[mt][nt][r] + bi;
                    const float v1 = __shfl_xor(v0, 1);
                    if (!(m & 1)) {
                        const unsigned pk = (unsigned)f2bf(v0) | ((unsigned)f2bf(v1) << 16);
                        out[(size_t)(rows0 + mt * 16 + kq * 4 + r) * stride + nt * 8 + (m >> 1)] = pk;
                    }
                }
            }
        }
    }
}

// ---- CSR build: degree histogram -> hierarchical scan -> bucket scatter -----
__global__ __launch_bounds__(256) void deg_k(const int* __restrict__ ei, int* __restrict__ deg)
{
    const int e = blockIdx.x * 256 + threadIdx.x;
    if (e < EE) atomicAdd(&deg[ei[EE + e]], 1);
}

__global__ __launch_bounds__(256) void scan_part(const int* __restrict__ deg,
                                                 int* __restrict__ bsum)
{
    __shared__ int red[256];
    const int base = blockIdx.x * SCAN_ELEM + threadIdx.x * 4;
    int s = 0;
#pragma unroll
    for (int j = 0; j < 4; j++) { const int i = base + j; if (i < NN) s += deg[i]; }
    red[threadIdx.x] = s;
    __syncthreads();
    for (int st = 128; st > 0; st >>= 1) {
        if (threadIdx.x < st) red[threadIdx.x] += red[threadIdx.x + st];
        __syncthreads();
    }
    if (threadIdx.x == 0) bsum[blockIdx.x] = red[0];
}

__global__ __launch_bounds__(128) void scan_top(const int* __restrict__ bsum,
                                                int* __restrict__ boff)
{
    __shared__ int buf[128];
    const int v = (threadIdx.x < NSB) ? bsum[threadIdx.x] : 0;
    buf[threadIdx.x] = v;
    __syncthreads();
    for (int s = 1; s < 128; s <<= 1) {
        const int t = (threadIdx.x >= s) ? buf[threadIdx.x - s] : 0;
        __syncthreads();
        buf[threadIdx.x] += t;
        __syncthreads();
    }
    if (threadIdx.x < NSB) boff[threadIdx.x] = buf[threadIdx.x] - v;
}

__global__ __launch_bounds__(256) void scan_final(const int* __restrict__ deg,
                                                  const int* __restrict__ boff,
                                                  int* __restrict__ off,
                                                  int* __restrict__ cursor)
{
    __shared__ int tsum[256];
    const int base = blockIdx.x * SCAN_ELEM + threadIdx.x * 4;
    int vals[4];
    int s = 0;
#pragma unroll
    for (int j = 0; j < 4; j++) {
        const int i = base + j;
        vals[j] = (i < NN) ? deg[i] : 0;
        s += vals[j];
    }
    tsum[threadIdx.x] = s;
    __syncthreads();
    for (int st = 1; st < 256; st <<= 1) {
        const int t = (threadIdx.x >= st) ? tsum[threadIdx.x - st] : 0;
        __syncthreads();
        tsum[threadIdx.x] += t;
        __syncthreads();
    }
    int ex = boff[blockIdx.x] + tsum[threadIdx.x] - s;
#pragma unroll
    for (int j = 0; j < 4; j++) {
        const int i = base + j;
        if (i < NN) { off[i] = ex; cursor[i] = ex; }
        ex += vals[j];
    }
    if (blockIdx.x == NSB - 1 && threadIdx.x == 255)
        off[NN] = boff[blockIdx.x] + tsum[255];
}

// bucket: write src node id AND reordered edge_attr at CSR slot.
__global__ __launch_bounds__(256) void bucket_k(const int* __restrict__ ei,
                                                const float* __restrict__ ea,
                                                int* __restrict__ cursor,
                                                int* __restrict__ esrc,
                                                float4* __restrict__ eaf)
{
    const int e = blockIdx.x * 256 + threadIdx.x;
    if (e < EE) {
        const int d = ei[EE + e];
        const int p = atomicAdd(&cursor[d], 1);
        esrc[p] = ei[e];
        eaf[p] = *(const float4*)(ea + (size_t)e * 4);
    }
}

__global__ __launch_bounds__(256) void cnt_k(const int* __restrict__ batch,
                                             float* __restrict__ cnt)
{
    const int n = blockIdx.x * 256 + threadIdx.x;
    if (n < NN) atomicAdd(&cnt[batch[n]], 1.0f);
}

// ---- Fused edge stage: one wave per dst node, 4 edges in flight, 2-deep ----
// pipeline on the K/V gathers. BLOCK = 1024 threads = 16 waves = 16 nodes:
// fewer, longer-lived workgroups keep 32 waves/CU resident (the 256-thread
// version measured only ~47% occupancy -> latency-bound underfill).
// Lane = slot*16 + c8; slot in [0,4): edge slot; c8 in [0,16): 8 channels
// (one dwordx4 of packed bf16 at KVb[src]+c8*4, V at +64 dwords).
// Algebra (e = We.a linear):  q.(K+e) = q.K + a.(We^T q); the per-lane
// partial qep[d] folds into the existing per-edge shuffle reduce, and
// sum(alpha*(V+e)) = sum(alpha*V) + We.(sum(alpha*a)) with running s4.
// Epilogue is distributed: every lane owns 2 channels (c = c8*8 + slot*2).
// fuse_pool=0: out = relu(msg/den + skip) -> bf16 Hb (next GEMM input).
// fuse_pool=1: out = msg/den + skip -> atomicAdd into pooled[batch[n]].
__global__ __launch_bounds__(1024) void edge_fused(
    const int* __restrict__ esrc, const float4* __restrict__ eaf,
    const float* __restrict__ We,
    const unsigned* __restrict__ Qb, const unsigned* __restrict__ KVb,
    const int* __restrict__ off, const float* __restrict__ S,
    unsigned short* __restrict__ Hb,
    const int* __restrict__ batch, float* __restrict__ pooled,
    int fuse_pool)
{
    const int lane = threadIdx.x & 63;
    const int slot = lane >> 4;          // edge slot 0..3
    const int c8   = lane & 15;          // channel group: channels c8*8 .. +7
    const int cb   = c8 * 8;
    const int ceq  = cb + slot * 2;      // this lane's epilogue channel pair
    const int n = blockIdx.x * 16 + (threadIdx.x >> 6);

    const int beg = off[n], end = off[n + 1];

    // issue independent loads early: skip pair + q row
    const float2 sk2 = *(const float2*)(S + (size_t)n * HC + ceq);
    const uint4 qv = *(const uint4*)(Qb + (size_t)n * 64 + c8 * 4);
    f32x2 q2[4];
    q2[0] = unpk2(qv.x); q2[1] = unpk2(qv.y);
    q2[2] = unpk2(qv.z); q2[3] = unpk2(qv.w);

    // per-lane qe partials over my 8 channels (NOT reduced here; folded into
    // the per-edge shuffle reduce together with q.K)
    float qep[4];
#pragma unroll
    for (int d = 0; d < 4; d++) {
        const float4 wa = *(const float4*)(We + d * HC + cb);
        const float4 wb = *(const float4*)(We + d * HC + cb + 4);
        qep[d] = wa.x * q2[0].x + wa.y * q2[0].y + wa.z * q2[1].x + wa.w * q2[1].y
               + wb.x * q2[2].x + wb.y * q2[2].y + wb.z * q2[3].x + wb.w * q2[3].y;
    }

    f32x2 num2[4] = {(f32x2){0.f, 0.f}, (f32x2){0.f, 0.f},
                     (f32x2){0.f, 0.f}, (f32x2){0.f, 0.f}};
    f32x4 s4 = (f32x4){0.f, 0.f, 0.f, 0.f};
    float den = 0.f;

    auto COMPUTE = [&](const uint4& ku, const uint4& vu, const float4& ac, bool act) {
        f32x2 t2 = q2[0] * unpk2(ku.x);
        t2 += q2[1] * unpk2(ku.y);
        t2 += q2[2] * unpk2(ku.z);
        t2 += q2[3] * unpk2(ku.w);
        float tot = t2.x + t2.y
                  + ac.x * qep[0] + ac.y * qep[1] + ac.z * qep[2] + ac.w * qep[3];
        tot += __shfl_xor(tot, 1);            // 4-lane head group reduce
        tot += __shfl_xor(tot, 2);
        float al = __expf(tot * 0.17677669529663687f);   // 1/sqrt(32)
        if (!act) al = 0.f;
        num2[0] += unpk2(vu.x) * al;
        num2[1] += unpk2(vu.y) * al;
        num2[2] += unpk2(vu.z) * al;
        num2[3] += unpk2(vu.w) * al;
        s4.x += ac.x * al; s4.y += ac.y * al;
        s4.z += ac.z * al; s4.w += ac.w * al;
        den += al;
    };

    if (beg < end) {
        const int e1 = end - 1;
        int p0 = beg + slot; if (p0 > e1) p0 = e1;
        const int srcA = esrc[p0];
        const float4 aA = eaf[p0];
        const unsigned* kvA = KVb + (size_t)srcA * 128 + c8 * 4;
        const uint4 kA = *(const uint4*)kvA;
        const uint4 vA = *(const uint4*)(kvA + 64);
        if (beg + 4 < end) {
            // second quad issued BEFORE first compute: 2-deep MLP
            int p1 = beg + 4 + slot; if (p1 > e1) p1 = e1;
            const int srcB = esrc[p1];
            float4 aB = eaf[p1];
            const unsigned* kvB = KVb + (size_t)srcB * 128 + c8 * 4;
            uint4 kB = *(const uint4*)kvB;
            uint4 vB = *(const uint4*)(kvB + 64);
            COMPUTE(kA, vA, aA, true);        // deg>=5 => all 4 slots active
            int base = beg + 4;
            for (;;) {
                if (base + 4 < end) {
                    int pn = base + 4 + slot; if (pn > e1) pn = e1;
                    const int srcN = esrc[pn];       // index prefetch 1 ahead
                    const float4 aN = eaf[pn];
                    COMPUTE(kB, vB, aB, (base + slot) < end);
                    const unsigned* kvN = KVb + (size_t)srcN * 128 + c8 * 4;
                    kB = *(const uint4*)kvN;
                    vB = *(const uint4*)(kvN + 64);
                    aB = aN;
                    base += 4;
                } else {
                    COMPUTE(kB, vB, aB, (base + slot) < end);
                    break;
                }
            }
        } else {
            COMPUTE(kA, vA, aA, (beg + slot) < end);
        }
    }

    // cross-slot combine (once per node)
#pragma unroll
    for (int j = 0; j < 4; j++) {
        num2[j].x += __shfl_xor(num2[j].x, 16);
        num2[j].y += __shfl_xor(num2[j].y, 16);
        num2[j].x += __shfl_xor(num2[j].x, 32);
        num2[j].y += __shfl_xor(num2[j].y, 32);
    }
    s4.x += __shfl_xor(s4.x, 16); s4.y += __shfl_xor(s4.y, 16);
    s4.z += __shfl_xor(s4.z, 16); s4.w += __shfl_xor(s4.w, 16);
    s4.x += __shfl_xor(s4.x, 32); s4.y += __shfl_xor(s4.y, 32);
    s4.z += __shfl_xor(s4.z, 32); s4.w += __shfl_xor(s4.w, 32);
    den += __shfl_xor(den, 16);
    den += __shfl_xor(den, 32);
    const float inv = 1.f / (den + 1e-16f);

    // my channel pair (static-index selection)
    f32x2 mynum = slot == 0 ? num2[0] : slot == 1 ? num2[1]
                : slot == 2 ? num2[2] : num2[3];
    // edge-attr contribution for my 2 channels: We . s4
    float ev0 = 0.f, ev1 = 0.f;
#pragma unroll
    for (int d = 0; d < 4; d++) {
        const float2 wd = *(const float2*)(We + d * HC + ceq);
        const float sd = d == 0 ? s4.x : d == 1 ? s4.y : d == 2 ? s4.z : s4.w;
        ev0 += sd * wd.x;
        ev1 += sd * wd.y;
    }
    const float o0 = (mynum.x + ev0) * inv + sk2.x;
    const float o1 = (mynum.y + ev1) * inv + sk2.y;

    if (!fuse_pool) {
        const float r0 = fmaxf(o0, 0.f), r1 = fmaxf(o1, 0.f);
        const unsigned pk = (unsigned)f2bf(r0) | ((unsigned)f2bf(r1) << 16);
        *(unsigned*)(Hb + (size_t)n * HC + ceq) = pk;   // 64 lanes = 256B row
    } else {
        const int b = batch[n];
        atomicAdd(pooled + (size_t)b * HC + ceq,     o0);
        atomicAdd(pooled + (size_t)b * HC + ceq + 1, o1);
    }
}

__global__ __launch_bounds__(256) void head_k(
    const float* __restrict__ pooled, const float* __restrict__ cnt,
    const int* __restrict__ rt, const float* __restrict__ hW,
    const float* __restrict__ hb, float* __restrict__ out)
{
    const int lane = threadIdx.x & 63;
    const int b = blockIdx.x * 4 + (threadIdx.x >> 6);
    if (b >= BB) return;
    const int t = rt[b];
    const int c = lane * 2;
    const float2 p2 = *(const float2*)(pooled + (size_t)b * HC + c);
    const float2 w2 = *(const float2*)(hW + (size_t)t * HC + c);
    float part = p2.x * w2.x + p2.y * w2.y;
    part += __shfl_xor(part, 1);
    part += __shfl_xor(part, 2);
    part += __shfl_xor(part, 4);
    part += __shfl_xor(part, 8);
    part += __shfl_xor(part, 16);
    part += __shfl_xor(part, 32);
    if (lane == 0) out[b] = part / fmaxf(cnt[b], 1.0f) + hb[t];
}

extern "C" void kernel_launch(void* const* d_in, const int* in_sizes, int n_in,
                              void* d_out, int out_size, void* d_ws, size_t ws_size,
                              hipStream_t stream) {
    const float* x      = (const float*)d_in[0];
    const int*   ei     = (const int*)d_in[1];
    const float* ea     = (const float*)d_in[2];
    const int*   batch  = (const int*)d_in[3];
    const int*   rt     = (const int*)d_in[4];

    // workspace layout — big 16B-aligned arrays first; ~166 MB total
    float* ws     = (float*)d_ws;
    float* Hbuf   = ws;                                   // 12,800,000 f (S plane)
    unsigned* Qb  = (unsigned*)(ws + 12800000);           // 6,400,000 u32 (packed bf16)
    unsigned* KVb = Qb + 6400000;                         // 12,800,000 u32 (K|V interleaved)
    unsigned short* Abf = (unsigned short*)(KVb + 12800000); // 12,800,000 us
    float4* eaf   = (float4*)(Abf + 12800000);            // 500,000 float4
    unsigned short* Wt = (unsigned short*)(eaf + 500000); // 65,536 us
    float* pooled = (float*)(Wt + 65536);                 // 524,288 f
    float* cnt    = pooled + 524288;                      // 4,096 f
    int*   esrc   = (int*)(cnt + 4096);                   // 500,000 i
    int*   deg    = esrc + 500000;                        // 100,000 i
    int*   off    = deg + 100000;                         // 100,001 i (+pad)
    int*   cursor = off + 100004;                         // 100,000 i
    int*   bsum   = cursor + 100000;                      // 128 i
    int*   boff   = bsum + 128;                           // 128 i

    // ---- CSR build (graph identical every call; ws re-poisoned each call)
    hipMemsetAsync(deg, 0, 100000 * sizeof(int), stream);
    deg_k<<<(EE + 255) / 256, 256, 0, stream>>>(ei, deg);
    scan_part<<<NSB, 256, 0, stream>>>(deg, bsum);
    scan_top<<<1, 128, 0, stream>>>(bsum, boff);
    scan_final<<<NSB, 256, 0, stream>>>(deg, boff, off, cursor);
    bucket_k<<<(EE + 255) / 256, 256, 0, stream>>>(ei, ea, cursor, esrc, eaf);

    // pooled/cnt zero + counts (pooled is written only by layer-3 edge_fused)
    hipMemsetAsync(pooled, 0, (size_t)(BB * HC + BB) * sizeof(float), stream);
    cnt_k<<<(NN + 255) / 256, 256, 0, stream>>>(batch, cnt);

    // layer-1 input -> bf16
    conv_x<<<(NN * 64 / 4 + 255) / 256, 256, 0, stream>>>(x, Abf, NN * 64 / 4);

    for (int l = 0; l < 3; l++) {
        const int K = (l == 0) ? 64 : 128;
        const float *Wq, *Wk, *Wv, *Wsk, *bq, *bk, *bv, *bs, *We;
        if (l == 0) {
            Wq = (const float*)d_in[5];  bq = (const float*)d_in[6];
            Wk = (const float*)d_in[7];  bk = (const float*)d_in[8];
            Wv = (const float*)d_in[9];  bv = (const float*)d_in[10];
            We = (const float*)d_in[11];
            Wsk= (const float*)d_in[12]; bs = (const float*)d_in[13];
        } else {
            const int j = l - 1;
            Wq = (const float*)d_in[14] + (size_t)j * HC * HC;  bq = (const float*)d_in[15] + j * HC;
            Wk = (const float*)d_in[16] + (size_t)j * HC * HC;  bk = (const float*)d_in[17] + j * HC;
            Wv = (const float*)d_in[18] + (size_t)j * HC * HC;  bv = (const float*)d_in[19] + j * HC;
            We = (const float*)d_in[20] + (size_t)j * 4 * HC;
            Wsk= (const float*)d_in[21] + (size_t)j * HC * HC;  bs = (const float*)d_in[22] + j * HC;
        }

        prep_w<<<(4 * K * 128 + 255) / 256, 256, 0, stream>>>(Wq, Wk, Wv, Wsk, Wt, K);
        if (K == 64)
            gemm_mfma<2><<<NN / 32, 256, 0, stream>>>(Abf, Wt, bq, bk, bv, bs, Qb, KVb, Hbuf);
        else
            gemm_mfma<4><<<NN / 32, 256, 0, stream>>>(Abf, Wt, bq, bk, bv, bs, Qb, KVb, Hbuf);
        edge_fused<<<NN / 16, 1024, 0, stream>>>(esrc, eaf, We, Qb, KVb, off,
                                                 Hbuf, Abf, batch, pooled,
                                                 l == 2 ? 1 : 0);
    }

    head_k<<<BB / 4, 256, 0, stream>>>(pooled, cnt, rt,
        (const float*)d_in[23], (const float*)d_in[24], (float*)d_out);
}

// Round 5
// 664.577 us; speedup vs baseline: 1.0887x; 1.0887x over previous
//
#include <hip/hip_runtime.h>
#include <hip/hip_bf16.h>

#define NN 100000
#define EE 500000
#define BB 4096
#define HC 128
#define SCAN_ELEM 1024
#define NSB ((NN + SCAN_ELEM - 1) / SCAN_ELEM)   // 98 blocks

typedef __bf16 bf16_t;
typedef bf16_t bf16x8 __attribute__((ext_vector_type(8)));
typedef float f32x4 __attribute__((ext_vector_type(4)));
typedef float f32x2 __attribute__((ext_vector_type(2)));

__device__ __forceinline__ unsigned short f2bf(float f) {
    unsigned u = __builtin_bit_cast(unsigned, f);
    u += 0x7FFFu + ((u >> 16) & 1u);            // RNE
    return (unsigned short)(u >> 16);
}
__device__ __forceinline__ float bflo(unsigned u) {   // low bf16 -> f32
    return __builtin_bit_cast(float, u << 16);
}
__device__ __forceinline__ float bfhi(unsigned u) {   // high bf16 -> f32
    return __builtin_bit_cast(float, u & 0xFFFF0000u);
}
__device__ __forceinline__ f32x2 unpk2(unsigned u) {  // packed pair -> 2 f32
    return (f32x2){ bflo(u), bfhi(u) };
}

// ---- convert + transpose weights: W[k,n] fp32 -> Wt[p][n*K+k] bf16 ---------
__global__ __launch_bounds__(256) void prep_w(
    const float* __restrict__ Wq, const float* __restrict__ Wk,
    const float* __restrict__ Wv, const float* __restrict__ Ws,
    unsigned short* __restrict__ Wt, int K)
{
    const int g = blockIdx.x * 256 + threadIdx.x;
    const int per = K * 128;
    if (g >= 4 * per) return;
    const int p = g / per, r = g - p * per;
    const int k = r >> 7, n = r & 127;
    const float* W = p == 0 ? Wq : p == 1 ? Wk : p == 2 ? Wv : Ws;
    Wt[(size_t)p * per + (size_t)n * K + k] = f2bf(W[k * 128 + n]);
}

// ---- MFMA GEMM: block = 4 waves = 4 planes, 32-row tile, 128 cols ----------
// ALL outputs packed bf16 (pair per dword), merged planes to cut HBM bytes:
//   QSb[node] = [ Q : 64 dwords | S(skip) : 64 dwords ]   (stride 128)
//   KVb[node] = [ K : 64 dwords | V       : 64 dwords ]   (stride 128)
// F32A=1: A is fp32 (layer-1 x), converted to bf16 fragments in-register
// (kills the separate conv_x pass; 4 planes share rows via L1).
template<int NKT, int F32A>
__global__ __launch_bounds__(256) void gemm_mfma(
    const unsigned short* __restrict__ Abf,
    const float* __restrict__ xf,
    const unsigned short* __restrict__ Wt,
    const float* __restrict__ bq, const float* __restrict__ bk,
    const float* __restrict__ bv, const float* __restrict__ bs,
    unsigned* __restrict__ QSb, unsigned* __restrict__ KVb)
{
    constexpr int K = NKT * 32;
    const int lane = threadIdx.x & 63;
    const int p = threadIdx.x >> 6;              // wave == plane
    const int m = lane & 15, kq = lane >> 4;
    const int rows0 = blockIdx.x * 32;

    const unsigned short* Wp = Wt + (size_t)p * 128 * K;
    const float* bias = p == 0 ? bq : p == 1 ? bk : p == 2 ? bv : bs;

    bf16x8 a[2][NKT];
#pragma unroll
    for (int mt = 0; mt < 2; mt++)
#pragma unroll
        for (int kt = 0; kt < NKT; kt++) {
            if constexpr (F32A) {
                const float* pr = xf + (size_t)(rows0 + mt * 16 + m) * K + kt * 32 + kq * 8;
                const float4 f0 = *(const float4*)pr;
                const float4 f1 = *(const float4*)(pr + 4);
                union { bf16x8 v; unsigned short u8[8]; } cv;
                cv.u8[0] = f2bf(f0.x); cv.u8[1] = f2bf(f0.y);
                cv.u8[2] = f2bf(f0.z); cv.u8[3] = f2bf(f0.w);
                cv.u8[4] = f2bf(f1.x); cv.u8[5] = f2bf(f1.y);
                cv.u8[6] = f2bf(f1.z); cv.u8[7] = f2bf(f1.w);
                a[mt][kt] = cv.v;
            } else {
                a[mt][kt] = *(const bf16x8*)(Abf + (size_t)(rows0 + mt * 16 + m) * K + kt * 32 + kq * 8);
            }
        }

    f32x4 acc[2][8];
#pragma unroll
    for (int mt = 0; mt < 2; mt++)
#pragma unroll
        for (int nt = 0; nt < 8; nt++)
            acc[mt][nt] = (f32x4){0.f, 0.f, 0.f, 0.f};

#pragma unroll
    for (int nt = 0; nt < 8; nt++) {
#pragma unroll
        for (int kt = 0; kt < NKT; kt++) {
            const bf16x8 b = *(const bf16x8*)(Wp + (size_t)(nt * 16 + m) * K + kt * 32 + kq * 8);
            acc[0][nt] = __builtin_amdgcn_mfma_f32_16x16x32_bf16(a[0][kt], b, acc[0][nt], 0, 0, 0);
            acc[1][nt] = __builtin_amdgcn_mfma_f32_16x16x32_bf16(a[1][kt], b, acc[1][nt], 0, 0, 0);
        }
    }

    unsigned* out = p == 0 ? QSb : p == 1 ? KVb : p == 2 ? (KVb + 64) : (QSb + 64);
#pragma unroll
    for (int nt = 0; nt < 8; nt++) {
        const float bi = bias[nt * 16 + m];
#pragma unroll
        for (int mt = 0; mt < 2; mt++) {
#pragma unroll
            for (int r = 0; r < 4; r++) {
                const float v0 = acc[mt][nt][r] + bi;
                const float v1 = __shfl_xor(v0, 1);
                if (!(m & 1)) {
                    const unsigned pk = (unsigned)f2bf(v0) | ((unsigned)f2bf(v1) << 16);
                    out[(size_t)(rows0 + mt * 16 + kq * 4 + r) * 128 + nt * 8 + (m >> 1)] = pk;
                }
            }
        }
    }
}

// ---- CSR build: degree histogram -> hierarchical scan -> bucket scatter -----
__global__ __launch_bounds__(256) void deg_k(const int* __restrict__ ei, int* __restrict__ deg)
{
    const int e = blockIdx.x * 256 + threadIdx.x;
    if (e < EE) atomicAdd(&deg[ei[EE + e]], 1);
}

__global__ __launch_bounds__(256) void scan_part(const int* __restrict__ deg,
                                                 int* __restrict__ bsum)
{
    __shared__ int red[256];
    const int base = blockIdx.x * SCAN_ELEM + threadIdx.x * 4;
    int s = 0;
#pragma unroll
    for (int j = 0; j < 4; j++) { const int i = base + j; if (i < NN) s += deg[i]; }
    red[threadIdx.x] = s;
    __syncthreads();
    for (int st = 128; st > 0; st >>= 1) {
        if (threadIdx.x < st) red[threadIdx.x] += red[threadIdx.x + st];
        __syncthreads();
    }
    if (threadIdx.x == 0) bsum[blockIdx.x] = red[0];
}

__global__ __launch_bounds__(128) void scan_top(const int* __restrict__ bsum,
                                                int* __restrict__ boff)
{
    __shared__ int buf[128];
    const int v = (threadIdx.x < NSB) ? bsum[threadIdx.x] : 0;
    buf[threadIdx.x] = v;
    __syncthreads();
    for (int s = 1; s < 128; s <<= 1) {
        const int t = (threadIdx.x >= s) ? buf[threadIdx.x - s] : 0;
        __syncthreads();
        buf[threadIdx.x] += t;
        __syncthreads();
    }
    if (threadIdx.x < NSB) boff[threadIdx.x] = buf[threadIdx.x] - v;
}

__global__ __launch_bounds__(256) void scan_final(const int* __restrict__ deg,
                                                  const int* __restrict__ boff,
                                                  int* __restrict__ off,
                                                  int* __restrict__ cursor)
{
    __shared__ int tsum[256];
    const int base = blockIdx.x * SCAN_ELEM + threadIdx.x * 4;
    int vals[4];
    int s = 0;
#pragma unroll
    for (int j = 0; j < 4; j++) {
        const int i = base + j;
        vals[j] = (i < NN) ? deg[i] : 0;
        s += vals[j];
    }
    tsum[threadIdx.x] = s;
    __syncthreads();
    for (int st = 1; st < 256; st <<= 1) {
        const int t = (threadIdx.x >= st) ? tsum[threadIdx.x - st] : 0;
        __syncthreads();
        tsum[threadIdx.x] += t;
        __syncthreads();
    }
    int ex = boff[blockIdx.x] + tsum[threadIdx.x] - s;
#pragma unroll
    for (int j = 0; j < 4; j++) {
        const int i = base + j;
        if (i < NN) { off[i] = ex; cursor[i] = ex; }
        ex += vals[j];
    }
    if (blockIdx.x == NSB - 1 && threadIdx.x == 255)
        off[NN] = boff[blockIdx.x] + tsum[255];
}

// bucket: write src node id AND reordered edge_attr at CSR slot.
__global__ __launch_bounds__(256) void bucket_k(const int* __restrict__ ei,
                                                const float* __restrict__ ea,
                                                int* __restrict__ cursor,
                                                int* __restrict__ esrc,
                                                float4* __restrict__ eaf)
{
    const int e = blockIdx.x * 256 + threadIdx.x;
    if (e < EE) {
        const int d = ei[EE + e];
        const int p = atomicAdd(&cursor[d], 1);
        esrc[p] = ei[e];
        eaf[p] = *(const float4*)(ea + (size_t)e * 4);
    }
}

__global__ __launch_bounds__(256) void cnt_k(const int* __restrict__ batch,
                                             float* __restrict__ cnt)
{
    const int n = blockIdx.x * 256 + threadIdx.x;
    if (n < NN) atomicAdd(&cnt[batch[n]], 1.0f);
}

// ---- Fused edge stage: one wave per dst node, 4 edges in flight. -----------
// Lane = slot*16 + c8; slot in [0,4): edge slot; c8 in [0,16): 8 channels
// (one dwordx4 of packed bf16 at KVb[src]*128 + c8*4, V at +64 dwords).
// Skip is bf16-packed in the same row as Q: QSb[n]*128 + 64 + c8*4 + slot
// holds this lane's channel pair (halves the skip HBM stream vs f32).
// Algebra (e = We.a linear):  q.(K+e) = q.K + a.(We^T q); per-lane partial
// qep[d] folds into the per-edge shuffle reduce, and sum(alpha*(V+e)) =
// sum(alpha*V) + We.(sum(alpha*a)) with running s4.
// Epilogue distributed: every lane owns 2 channels (ceq = c8*8 + slot*2).
// fuse_pool=0: out = relu(msg/den + skip) -> bf16 Hb (next GEMM input).
// fuse_pool=1: out = msg/den + skip -> atomicAdd into pooled[batch[n]].
__global__ __launch_bounds__(256) void edge_fused(
    const int* __restrict__ esrc, const float4* __restrict__ eaf,
    const float* __restrict__ We,
    const unsigned* __restrict__ QSb, const unsigned* __restrict__ KVb,
    const int* __restrict__ off,
    unsigned short* __restrict__ Hb,
    const int* __restrict__ batch, float* __restrict__ pooled,
    int fuse_pool)
{
    const int lane = threadIdx.x & 63;
    const int slot = lane >> 4;          // edge slot 0..3
    const int c8   = lane & 15;          // channel group: channels c8*8 .. +7
    const int cb   = c8 * 8;
    const int ceq  = cb + slot * 2;      // this lane's epilogue channel pair
    const int n = blockIdx.x * 4 + (threadIdx.x >> 6);

    const int beg = off[n], end = off[n + 1];

    // issue independent loads early: q row + bf16 skip pair
    const uint4 qv = *(const uint4*)(QSb + (size_t)n * 128 + c8 * 4);
    const unsigned sku = QSb[(size_t)n * 128 + 64 + c8 * 4 + slot];
    f32x2 q2[4];
    q2[0] = unpk2(qv.x); q2[1] = unpk2(qv.y);
    q2[2] = unpk2(qv.z); q2[3] = unpk2(qv.w);

    // per-lane qe partials over my 8 channels (reduced jointly with q.K)
    float qep[4];
#pragma unroll
    for (int d = 0; d < 4; d++) {
        const float4 wa = *(const float4*)(We + d * HC + cb);
        const float4 wb = *(const float4*)(We + d * HC + cb + 4);
        qep[d] = wa.x * q2[0].x + wa.y * q2[0].y + wa.z * q2[1].x + wa.w * q2[1].y
               + wb.x * q2[2].x + wb.y * q2[2].y + wb.z * q2[3].x + wb.w * q2[3].y;
    }

    f32x2 num2[4] = {(f32x2){0.f, 0.f}, (f32x2){0.f, 0.f},
                     (f32x2){0.f, 0.f}, (f32x2){0.f, 0.f}};
    f32x4 s4 = (f32x4){0.f, 0.f, 0.f, 0.f};
    float den = 0.f;

    if (beg < end) {
        const int e1 = end - 1;
        int p0 = beg + slot; if (p0 > e1) p0 = e1;
        int src = esrc[p0];
        float4 a4 = eaf[p0];
        for (int base = beg; base < end; base += 4) {
            const unsigned* kv = KVb + (size_t)src * 128 + c8 * 4;
            const uint4 ku = *(const uint4*)kv;
            const uint4 vu = *(const uint4*)(kv + 64);
            const float4 ac = a4;
            const bool act = (base + slot) < end;
            if (base + 4 < end) {                  // 1-ahead prefetch
                int pn = base + 4 + slot; if (pn > e1) pn = e1;
                src = esrc[pn]; a4 = eaf[pn];
            }
            f32x2 t2 = q2[0] * unpk2(ku.x);
            t2 += q2[1] * unpk2(ku.y);
            t2 += q2[2] * unpk2(ku.z);
            t2 += q2[3] * unpk2(ku.w);
            float tot = t2.x + t2.y
                      + ac.x * qep[0] + ac.y * qep[1] + ac.z * qep[2] + ac.w * qep[3];
            tot += __shfl_xor(tot, 1);            // 4-lane head group reduce
            tot += __shfl_xor(tot, 2);
            float al = __expf(tot * 0.17677669529663687f);   // 1/sqrt(32)
            if (!act) al = 0.f;
            num2[0] += unpk2(vu.x) * al;
            num2[1] += unpk2(vu.y) * al;
            num2[2] += unpk2(vu.z) * al;
            num2[3] += unpk2(vu.w) * al;
            s4.x += ac.x * al; s4.y += ac.y * al;
            s4.z += ac.z * al; s4.w += ac.w * al;
            den += al;
        }
    }

    // cross-slot combine (once per node)
#pragma unroll
    for (int j = 0; j < 4; j++) {
        num2[j].x += __shfl_xor(num2[j].x, 16);
        num2[j].y += __shfl_xor(num2[j].y, 16);
        num2[j].x += __shfl_xor(num2[j].x, 32);
        num2[j].y += __shfl_xor(num2[j].y, 32);
    }
    s4.x += __shfl_xor(s4.x, 16); s4.y += __shfl_xor(s4.y, 16);
    s4.z += __shfl_xor(s4.z, 16); s4.w += __shfl_xor(s4.w, 16);
    s4.x += __shfl_xor(s4.x, 32); s4.y += __shfl_xor(s4.y, 32);
    s4.z += __shfl_xor(s4.z, 32); s4.w += __shfl_xor(s4.w, 32);
    den += __shfl_xor(den, 16);
    den += __shfl_xor(den, 32);
    const float inv = 1.f / (den + 1e-16f);

    // my channel pair (static-index selection)
    f32x2 mynum = slot == 0 ? num2[0] : slot == 1 ? num2[1]
                : slot == 2 ? num2[2] : num2[3];
    // edge-attr contribution for my 2 channels: We . s4
    float ev0 = 0.f, ev1 = 0.f;
#pragma unroll
    for (int d = 0; d < 4; d++) {
        const float2 wd = *(const float2*)(We + d * HC + ceq);
        const float sd = d == 0 ? s4.x : d == 1 ? s4.y : d == 2 ? s4.z : s4.w;
        ev0 += sd * wd.x;
        ev1 += sd * wd.y;
    }
    const float o0 = (mynum.x + ev0) * inv + bflo(sku);
    const float o1 = (mynum.y + ev1) * inv + bfhi(sku);

    if (!fuse_pool) {
        const float r0 = fmaxf(o0, 0.f), r1 = fmaxf(o1, 0.f);
        const unsigned pk = (unsigned)f2bf(r0) | ((unsigned)f2bf(r1) << 16);
        *(unsigned*)(Hb + (size_t)n * HC + ceq) = pk;   // 64 lanes = 256B row
    } else {
        const int b = batch[n];
        atomicAdd(pooled + (size_t)b * HC + ceq,     o0);
        atomicAdd(pooled + (size_t)b * HC + ceq + 1, o1);
    }
}

__global__ __launch_bounds__(256) void head_k(
    const float* __restrict__ pooled, const float* __restrict__ cnt,
    const int* __restrict__ rt, const float* __restrict__ hW,
    const float* __restrict__ hb, float* __restrict__ out)
{
    const int lane = threadIdx.x & 63;
    const int b = blockIdx.x * 4 + (threadIdx.x >> 6);
    if (b >= BB) return;
    const int t = rt[b];
    const int c = lane * 2;
    const float2 p2 = *(const float2*)(pooled + (size_t)b * HC + c);
    const float2 w2 = *(const float2*)(hW + (size_t)t * HC + c);
    float part = p2.x * w2.x + p2.y * w2.y;
    part += __shfl_xor(part, 1);
    part += __shfl_xor(part, 2);
    part += __shfl_xor(part, 4);
    part += __shfl_xor(part, 8);
    part += __shfl_xor(part, 16);
    part += __shfl_xor(part, 32);
    if (lane == 0) out[b] = part / fmaxf(cnt[b], 1.0f) + hb[t];
}

extern "C" void kernel_launch(void* const* d_in, const int* in_sizes, int n_in,
                              void* d_out, int out_size, void* d_ws, size_t ws_size,
                              hipStream_t stream) {
    const float* x      = (const float*)d_in[0];
    const int*   ei     = (const int*)d_in[1];
    const float* ea     = (const float*)d_in[2];
    const int*   batch  = (const int*)d_in[3];
    const int*   rt     = (const int*)d_in[4];

    // workspace layout — big 16B-aligned arrays first; ~141 MB total
    unsigned* QSb = (unsigned*)d_ws;                      // 12,800,000 u32 (Q|S bf16)
    unsigned* KVb = QSb + 12800000;                       // 12,800,000 u32 (K|V bf16)
    unsigned short* Abf = (unsigned short*)(KVb + 12800000); // 12,800,000 us (h plane)
    float4* eaf   = (float4*)(Abf + 12800000);            // 500,000 float4
    unsigned short* Wt = (unsigned short*)(eaf + 500000); // 65,536 us
    float* pooled = (float*)(Wt + 65536);                 // 524,288 f
    float* cnt    = pooled + 524288;                      // 4,096 f
    int*   esrc   = (int*)(cnt + 4096);                   // 500,000 i
    int*   deg    = esrc + 500000;                        // 100,000 i
    int*   off    = deg + 100000;                         // 100,001 i (+pad)
    int*   cursor = off + 100004;                         // 100,000 i
    int*   bsum   = cursor + 100000;                      // 128 i
    int*   boff   = bsum + 128;                           // 128 i

    // ---- CSR build (graph identical every call; ws re-poisoned each call)
    hipMemsetAsync(deg, 0, 100000 * sizeof(int), stream);
    deg_k<<<(EE + 255) / 256, 256, 0, stream>>>(ei, deg);
    scan_part<<<NSB, 256, 0, stream>>>(deg, bsum);
    scan_top<<<1, 128, 0, stream>>>(bsum, boff);
    scan_final<<<NSB, 256, 0, stream>>>(deg, boff, off, cursor);
    bucket_k<<<(EE + 255) / 256, 256, 0, stream>>>(ei, ea, cursor, esrc, eaf);

    // pooled/cnt zero + counts (pooled is written only by layer-3 edge_fused)
    hipMemsetAsync(pooled, 0, (size_t)(BB * HC + BB) * sizeof(float), stream);
    cnt_k<<<(NN + 255) / 256, 256, 0, stream>>>(batch, cnt);

    for (int l = 0; l < 3; l++) {
        const int K = (l == 0) ? 64 : 128;
        const float *Wq, *Wk, *Wv, *Wsk, *bq, *bk, *bv, *bs, *We;
        if (l == 0) {
            Wq = (const float*)d_in[5];  bq = (const float*)d_in[6];
            Wk = (const float*)d_in[7];  bk = (const float*)d_in[8];
            Wv = (const float*)d_in[9];  bv = (const float*)d_in[10];
            We = (const float*)d_in[11];
            Wsk= (const float*)d_in[12]; bs = (const float*)d_in[13];
        } else {
            const int j = l - 1;
            Wq = (const float*)d_in[14] + (size_t)j * HC * HC;  bq = (const float*)d_in[15] + j * HC;
            Wk = (const float*)d_in[16] + (size_t)j * HC * HC;  bk = (const float*)d_in[17] + j * HC;
            Wv = (const float*)d_in[18] + (size_t)j * HC * HC;  bv = (const float*)d_in[19] + j * HC;
            We = (const float*)d_in[20] + (size_t)j * 4 * HC;
            Wsk= (const float*)d_in[21] + (size_t)j * HC * HC;  bs = (const float*)d_in[22] + j * HC;
        }

        prep_w<<<(4 * K * 128 + 255) / 256, 256, 0, stream>>>(Wq, Wk, Wv, Wsk, Wt, K);
        if (K == 64)
            gemm_mfma<2, 1><<<NN / 32, 256, 0, stream>>>(Abf, x, Wt, bq, bk, bv, bs, QSb, KVb);
        else
            gemm_mfma<4, 0><<<NN / 32, 256, 0, stream>>>(Abf, x, Wt, bq, bk, bv, bs, QSb, KVb);
        edge_fused<<<NN / 4, 256, 0, stream>>>(esrc, eaf, We, QSb, KVb, off,
                                               Abf, batch, pooled,
                                               l == 2 ? 1 : 0);
    }

    head_k<<<BB / 4, 256, 0, stream>>>(pooled, cnt, rt,
        (const float*)d_in[23], (const float*)d_in[24], (float*)d_out);
}